// Round 12
// baseline (1969.757 us; speedup 1.0000x reference)
//
#include <hip/hip_runtime.h>
#include <hip/hip_bf16.h>

#define GN 65536
#define GE 131072
#define GB 2048

typedef __attribute__((ext_vector_type(8))) short short8;
typedef __attribute__((ext_vector_type(4))) float floatx4;

static __device__ __forceinline__ float sigm(float x) { return 1.0f / (1.0f + __expf(-x)); }
static __device__ __forceinline__ float bf2f(unsigned short u) {
    union { unsigned int i; float f; } v; v.i = ((unsigned int)u) << 16; return v.f;
}
static __device__ __forceinline__ int geti(const void* p, long long i, int f64) {
    return f64 ? (int)((const long long*)p)[i] : ((const int*)p)[i];
}

// ---- batched per-tensor float dtype detector (one block per tensor) ----
struct DetectArgs { const void* src[17]; int nhalf[17]; int fi[17]; };
__global__ void k_dtype_all(DetectArgs a, int* __restrict__ flags) {
    const unsigned short* p = (const unsigned short*)a.src[blockIdx.x];
    const int n0 = a.nhalf[blockIdx.x];
    const int n = n0 < 16384 ? n0 : 16384;
    __shared__ unsigned int sAny[256], sOr[256];
    unsigned int any = 0, orEven = 0;
    for (int i = threadIdx.x; i < n; i += 256) {
        const unsigned short u = p[i];
        const float av = fabsf(bf2f(u));
        if (!(av <= 1e6f)) any = 1u;
        if ((i & 1) == 0) orEven |= u;
    }
    sAny[threadIdx.x] = any; sOr[threadIdx.x] = orEven;
    __syncthreads();
    for (int s = 128; s > 0; s >>= 1) {
        if (threadIdx.x < s) {
            sAny[threadIdx.x] |= sAny[threadIdx.x + s];
            sOr[threadIdx.x]  |= sOr[threadIdx.x + s];
        }
        __syncthreads();
    }
    if (threadIdx.x == 0) flags[a.fi[blockIdx.x]] = (sAny[0] || sOr[0] == 0u) ? 1 : 0;
}

// int64 detector, sampled
__global__ void k_i64(const unsigned int* __restrict__ p, long long nwords, int* __restrict__ flag) {
    const long long lim = nwords < 16384 ? nwords : 16384;
    __shared__ unsigned int s[256];
    unsigned int acc = 0;
    for (long long w = 1 + 2 * (long long)threadIdx.x; w < lim; w += 512) acc |= p[w];
    s[threadIdx.x] = acc;
    __syncthreads();
    for (int st = 128; st > 0; st >>= 1) {
        if (threadIdx.x < st) s[threadIdx.x] |= s[threadIdx.x + st];
        __syncthreads();
    }
    if (threadIdx.x == 0) *flag = (s[0] == 0u) ? 1 : 0;
}

// ---- batched f32 canonicalization of the 15 small float tensors ----
struct CvtArgs { const void* src[15]; float* dst[15]; int n[15]; int fi[15]; int pre[16]; };
__global__ void k_cvt_all(CvtArgs a, const int* __restrict__ flags) {
    const int b = blockIdx.x;
    int t = 0;
    while (t < 14 && b >= a.pre[t + 1]) ++t;
    const int i = (b - a.pre[t]) * 256 + threadIdx.x;
    if (i >= a.n[t]) return;
    const int f = flags[a.fi[t]];
    a.dst[t][i] = f ? ((const float*)a.src[t])[i] : bf2f(((const unsigned short*)a.src[t])[i]);
}

// transpose w2 [128][4096] -> w2T bf16 [4096][128]
__global__ __launch_bounds__(256) void k_t2(const void* __restrict__ src,
                                            __hip_bfloat16* __restrict__ w2T,
                                            const int* __restrict__ flag) {
    const int idx = blockIdx.x * 256 + threadIdx.x;
    const int kb8 = idx >> 12;
    const int n = idx & 4095;
    const int isf32 = *flag;
    short8 v;
    #pragma unroll
    for (int j = 0; j < 8; ++j) {
        const size_t si = (size_t)(kb8 * 8 + j) * 4096 + n;
        const float f = isf32 ? ((const float*)src)[si] : bf2f(((const unsigned short*)src)[si]);
        const __hip_bfloat16 b = __float2bfloat16(f);
        v[j] = *(const short*)&b;
    }
    *(short8*)(w2T + (size_t)n * 128 + kb8 * 8) = v;
}

// repack GRU weights: wpk[d][6][64]
__global__ void k_gpack(const float* __restrict__ w_ih, const float* __restrict__ w_hh,
                        float* __restrict__ wpk) {
    int idx = blockIdx.x * 256 + threadIdx.x;
    if (idx >= 64 * 384) return;
    const int d = idx / 384, rem = idx % 384, g = rem >> 6, k = rem & 63;
    wpk[idx] = (g < 3) ? w_ih[(g * 64 + d) * 64 + k] : w_hh[((g - 3) * 64 + d) * 64 + k];
}

__global__ void k_counts(const void* __restrict__ eidx, const int* __restrict__ fi64,
                         float* __restrict__ counts, int E_) {
    int e = blockIdx.x * 256 + threadIdx.x;
    if (e < E_) atomicAdd(&counts[geti(eidx, (long long)E_ + e, *fi64)], 1.0f);
}

__global__ void k_rowptr(const void* __restrict__ gi, const int* __restrict__ fi64,
                         int* __restrict__ rowptr, int N_, int B_) {
    int g = blockIdx.x * 256 + threadIdx.x;
    if (g > B_) return;
    const int f64 = *fi64;
    int lo = 0, hi = N_;
    while (lo < hi) { int mid = (lo + hi) >> 1; if (geti(gi, mid, f64) < g) lo = mid + 1; else hi = mid; }
    rowptr[g] = lo;
}

// lin0: out = relu(nf @ lin0_w + b)
__global__ __launch_bounds__(256) void k_lin0(const void* __restrict__ nf_raw,
                                              const float* __restrict__ w,
                                              const float* __restrict__ b,
                                              float* __restrict__ out,
                                              const int* __restrict__ flag) {
    const int ln = threadIdx.x >> 6;
    const int d = threadIdx.x & 63;
    const int n = blockIdx.x * 4 + ln;
    const int isf32 = *flag;
    __shared__ float s_nf[4][76];
    const size_t base = (size_t)n * 75;
    s_nf[ln][d] = isf32 ? ((const float*)nf_raw)[base + d] : bf2f(((const unsigned short*)nf_raw)[base + d]);
    if (d < 11) s_nf[ln][64 + d] = isf32 ? ((const float*)nf_raw)[base + 64 + d]
                                         : bf2f(((const unsigned short*)nf_raw)[base + 64 + d]);
    __syncthreads();
    float acc = b[d];
    #pragma unroll
    for (int i = 0; i < 75; ++i) acc += s_nf[ln][i] * w[i * 64 + d];
    out[(size_t)n * 64 + d] = fmaxf(acc, 0.0f);
}

// h1 = relu(ef @ w1 + b1) -> bf16
__global__ __launch_bounds__(256) void k1_h1(const void* __restrict__ ef_raw,
                                             const float* __restrict__ w1,
                                             const float* __restrict__ b1,
                                             __hip_bfloat16* __restrict__ h1,
                                             const int* __restrict__ flag) {
    const int le = threadIdx.x >> 7;
    const int j = threadIdx.x & 127;
    const int e = blockIdx.x * 2 + le;
    const int isf32 = *flag;
    __shared__ float efs[2][16];
    if (j < 16) {
        const size_t idx = (size_t)e * 16 + j;
        efs[le][j] = isf32 ? ((const float*)ef_raw)[idx] : bf2f(((const unsigned short*)ef_raw)[idx]);
    }
    __syncthreads();
    float acc = b1[j];
    #pragma unroll
    for (int i = 0; i < 16; ++i) acc += efs[le][i] * w1[i * 128 + j];
    h1[(size_t)e * 128 + j] = __float2bfloat16(fmaxf(acc, 0.0f));
}

// FUSED NNConv v4: A-fragments loaded DIRECT from global (no As LDS) ->
// LDS 52.7 KB -> 3 blocks/CU; full-K Bs (2 barriers/tile, 32 MFMA between).
__global__ __launch_bounds__(256) void k23_fused(const __hip_bfloat16* __restrict__ h1,
                                                 const __hip_bfloat16* __restrict__ w2T,
                                                 const float* __restrict__ b2,
                                                 const float* __restrict__ out,
                                                 const void* __restrict__ eidx,
                                                 const int* __restrict__ fi64,
                                                 float* __restrict__ agg) {
    __shared__ __hip_bfloat16 Bs[128][136];
    __shared__ float ylds[64][68];
    __shared__ int sidx[128];
    const int tid = threadIdx.x;
    const int e0 = blockIdx.x * 64;

    if (tid < 64) sidx[tid] = geti(eidx, e0 + tid, *fi64);
    else if (tid < 128) sidx[tid] = geti(eidx, (long long)GE + e0 + (tid - 64), *fi64);

    const int wave = tid >> 6, lane = tid & 63;
    const int wm = (wave >> 1) * 32;
    const int wn = (wave & 1) * 64;
    const int lr = lane & 15, quad = lane >> 4;

    // A fragments straight from global: 8 x int4 per lane, 16B contiguous each
    short8 af[2][4];
    #pragma unroll
    for (int mt = 0; mt < 2; ++mt)
        #pragma unroll
        for (int kk = 0; kk < 4; ++kk)
            af[mt][kk] = *(const short8*)(h1 + (size_t)(e0 + wm + mt * 16 + lr) * 128 + kk * 32 + quad * 8);

    __syncthreads();   // sidx visible
    {
        const int e = tid >> 2, d0 = (tid & 3) * 16;
        const float* srow = out + (size_t)sidx[e] * 64 + d0;
        #pragma unroll
        for (int j = 0; j < 4; ++j)
            *(float4*)(&ylds[e][d0 + j * 4]) = *(const float4*)(srow + j * 4);
    }
    // ylds visibility is covered by the post-Bs-staging barrier of tile 0.

    float msum[2][4][4] = {};

    for (int n0 = 0; n0 < 4096; n0 += 128) {
        floatx4 acc[2][4] = {};
        const int dcur = (n0 + wn) >> 6;
        #pragma unroll
        for (int i = 0; i < 8; ++i) {        // Bs: 128 rows x full K=128
            int chunk = i * 256 + tid;
            int r = chunk >> 4, c = (chunk & 15) * 8;
            *(int4*)(&Bs[r][c]) = *(const int4*)(w2T + (size_t)(n0 + r) * 128 + c);
        }
        __syncthreads();
        #pragma unroll
        for (int kk = 0; kk < 4; ++kk) {
            short8 bfr[4];
            #pragma unroll
            for (int nt = 0; nt < 4; ++nt)
                bfr[nt] = *(const short8*)(&Bs[wn + nt * 16 + lr][kk * 32 + quad * 8]);
            #pragma unroll
            for (int mt = 0; mt < 2; ++mt)
                #pragma unroll
                for (int nt = 0; nt < 4; ++nt)
                    acc[mt][nt] = __builtin_amdgcn_mfma_f32_16x16x32_bf16(af[mt][kk], bfr[nt], acc[mt][nt], 0, 0, 0);
        }
        __syncthreads();
        #pragma unroll
        for (int nt = 0; nt < 4; ++nt) {
            const float b2v = b2[n0 + wn + nt * 16 + lr];
            #pragma unroll
            for (int mt = 0; mt < 2; ++mt) {
                #pragma unroll
                for (int r = 0; r < 4; ++r) {
                    const int row = wm + mt * 16 + quad * 4 + r;
                    msum[mt][nt][r] = fmaf(ylds[row][dcur], acc[mt][nt][r] + b2v, msum[mt][nt][r]);
                }
            }
        }
    }
    #pragma unroll
    for (int mt = 0; mt < 2; ++mt)
        #pragma unroll
        for (int r = 0; r < 4; ++r) {
            const int row = wm + mt * 16 + quad * 4 + r;
            const int dn = sidx[64 + row];
            #pragma unroll
            for (int nt = 0; nt < 4; ++nt)
                atomicAdd(&agg[(size_t)dn * 64 + nt * 16 + lr], msum[mt][nt][r]);
        }
}

// GRU v3 (r10-verified): block = 64 nodes, 4 waves split the d-loop
__global__ __launch_bounds__(256) void k4_gru(const float* __restrict__ agg,
                                              const float* __restrict__ counts,
                                              const float* __restrict__ cbias,
                                              const float* __restrict__ wpk,
                                              const float* __restrict__ b_ih,
                                              const float* __restrict__ b_hh,
                                              float* __restrict__ out) {
    const int wv = threadIdx.x >> 6;
    const int lane = threadIdx.x & 63;
    const int nb0 = blockIdx.x * 64;
    __shared__ float sM[64][65], sH[64][65];

    #pragma unroll 4
    for (int i = 0; i < 16; ++i) {
        const int r = i * 4 + wv;
        sM[r][lane] = agg[(size_t)(nb0 + r) * 64 + lane];
        sH[r][lane] = out[(size_t)(nb0 + r) * 64 + lane];
    }
    __syncthreads();
    const float rcnt = 1.0f / fmaxf(counts[nb0 + lane], 1.0f);
    float m[64], h[64];
    #pragma unroll
    for (int k = 0; k < 64; ++k) {
        m[k] = fmaxf(sM[lane][k] * rcnt + cbias[k], 0.0f);
        h[k] = sH[lane][k];
    }
    __syncthreads();

    const int d0 = wv * 16;
    #pragma unroll 1
    for (int dd = 0; dd < 16; ++dd) {
        const int d = d0 + dd;
        const float* wr = wpk + d * 384;
        float a0 = b_ih[d], a1 = b_ih[64 + d], a2 = b_ih[128 + d];
        float g0 = b_hh[d], g1 = b_hh[64 + d], g2 = b_hh[128 + d];
        #pragma unroll
        for (int k = 0; k < 64; ++k) {
            a0 = fmaf(m[k], wr[k], a0);
            a1 = fmaf(m[k], wr[64 + k], a1);
            a2 = fmaf(m[k], wr[128 + k], a2);
            g0 = fmaf(h[k], wr[192 + k], g0);
            g1 = fmaf(h[k], wr[256 + k], g1);
            g2 = fmaf(h[k], wr[320 + k], g2);
        }
        const float r_ = sigm(a0 + g0);
        const float z  = sigm(a1 + g1);
        const float nn = tanhf(a2 + r_ * g2);
        const float hd = sH[lane][d];
        sM[lane][d] = (1.0f - z) * nn + z * hd;
    }
    __syncthreads();
    #pragma unroll 4
    for (int i = 0; i < 16; ++i) {
        const int r = i * 4 + wv;
        out[(size_t)(nb0 + r) * 64 + lane] = sM[r][lane];
    }
}

// FUSED Set2Set step: LSTM + 4-way wave-split online-softmax attention
__global__ __launch_bounds__(256) void k5_fused(float* __restrict__ qstar,
                                                float* __restrict__ hs, float* __restrict__ cs,
                                                const float* __restrict__ w_ih,
                                                const float* __restrict__ w_hh,
                                                const float* __restrict__ b_ih,
                                                const float* __restrict__ b_hh,
                                                const float* __restrict__ out,
                                                const int* __restrict__ rowptr) {
    const int g = blockIdx.x;
    const int j = threadIdx.x;
    __shared__ float qs[128], hv[64], gates[256], hval[64];
    __shared__ float smw[4], sSw[4], srw[4][64];
    if (j < 128) qs[j] = qstar[(size_t)g * 128 + j];
    else if (j < 192) hv[j - 128] = hs[(size_t)g * 64 + (j - 128)];
    __syncthreads();
    float acc = b_ih[j] + b_hh[j];
    for (int k4 = 0; k4 < 128; k4 += 4) {
        float4 v = *(const float4*)(w_ih + (size_t)j * 128 + k4);
        const float* pv = (const float*)&v;
        #pragma unroll
        for (int t = 0; t < 4; ++t) acc += qs[k4 + t] * pv[t];
    }
    for (int k4 = 0; k4 < 64; k4 += 4) {
        float4 v = *(const float4*)(w_hh + (size_t)j * 64 + k4);
        const float* pv = (const float*)&v;
        #pragma unroll
        for (int t = 0; t < 4; ++t) acc += hv[k4 + t] * pv[t];
    }
    gates[j] = acc;
    __syncthreads();
    if (j < 64) {
        const float ig = sigm(gates[j]);
        const float fg = sigm(gates[64 + j]);
        const float gg = tanhf(gates[128 + j]);
        const float og = sigm(gates[192 + j]);
        const float c = fg * cs[(size_t)g * 64 + j] + ig * gg;
        const float h = og * tanhf(c);
        cs[(size_t)g * 64 + j] = c;
        hs[(size_t)g * 64 + j] = h;
        qstar[(size_t)g * 128 + j] = h;
        hval[j] = h;
    }
    __syncthreads();
    const int wv = j >> 6, lane = j & 63;
    const int start = rowptr[g], end = rowptr[g + 1];
    const float q = hval[lane];
    float m = -3.4e38f, S = 0.0f, racc = 0.0f;
    for (int n = start + wv; n < end; n += 4) {
        const float ov = out[(size_t)n * 64 + lane];
        float p = ov * q;
        #pragma unroll
        for (int off = 1; off < 64; off <<= 1) p += __shfl_xor(p, off);
        if (p > m) {
            const float sc = __expf(m - p);
            S = S * sc + 1.0f;
            racc = racc * sc + ov;
            m = p;
        } else {
            const float w = __expf(p - m);
            S += w;
            racc += w * ov;
        }
    }
    if (lane == 0) { smw[wv] = m; sSw[wv] = S; }
    srw[wv][lane] = racc;
    __syncthreads();
    if (wv == 0) {
        const float mstar = fmaxf(fmaxf(smw[0], smw[1]), fmaxf(smw[2], smw[3]));
        float Ssum = 0.0f, rsum = 0.0f;
        #pragma unroll
        for (int i = 0; i < 4; ++i) {
            const float sc = __expf(smw[i] - mstar);
            Ssum += sSw[i] * sc;
            rsum += srw[i][lane] * sc;
        }
        qstar[(size_t)g * 128 + 64 + lane] = rsum / (Ssum + 1e-16f);
    }
}

__global__ void k_out(const float* __restrict__ qstar, const float* __restrict__ outb,
                      float* __restrict__ dst, int nq, int nfeat, int out_n) {
    int i = blockIdx.x * 256 + threadIdx.x;
    if (i >= out_n) return;
    float v = 0.0f;
    if (i < nq) v = qstar[i];
    else if (i - nq < nfeat) v = outb[i - nq];
    dst[i] = v;
}

extern "C" void kernel_launch(void* const* d_in, const int* in_sizes, int n_in,
                              void* d_out, int out_size, void* d_ws, size_t ws_size,
                              hipStream_t stream) {
    constexpr int N = GN, E = GE, B = GB;

    char* ws = (char*)d_ws;
    size_t off = 0;
    auto alloc = [&](size_t bytes) { size_t o = off; off = (off + bytes + 255) & ~(size_t)255; return o; };

    int*   fl     = (int*)  (ws + alloc(19 * 4));
    int*   flagE  = (int*)  (ws + alloc(256));
    int*   flagG  = (int*)  (ws + alloc(256));
    float* counts = (float*)(ws + alloc((size_t)N * 4));
    int*   rowptr = (int*)  (ws + alloc((size_t)(B + 1) * 4));
    float* outbuf = (float*)(ws + alloc((size_t)N * 64 * 4));
    float* agg    = (float*)(ws + alloc((size_t)N * 64 * 4));
    float* qstar  = (float*)(ws + alloc((size_t)B * 128 * 4));
    float* hsb    = (float*)(ws + alloc((size_t)B * 64 * 4));
    float* csb    = (float*)(ws + alloc((size_t)B * 64 * 4));
    __hip_bfloat16* h1  = (__hip_bfloat16*)(ws + alloc((size_t)E * 128 * 2));
    __hip_bfloat16* w2T = (__hip_bfloat16*)(ws + alloc((size_t)4096 * 128 * 2));
    float* wpk    = (float*)(ws + alloc((size_t)64 * 384 * 4));

    const int fidx[15]  = {4, 5, 6, 7, 8, 9, 10, 11, 12, 13, 14, 15, 16, 17, 18};
    const int fsize[15] = {75 * 64, 64, 16 * 128, 128, 128 * 4096, 4096, 64,
                           192 * 64, 192 * 64, 192, 192, 256 * 128, 256 * 64, 256, 256};
    float* F[19] = {};
    for (int t = 0; t < 15; ++t) F[fidx[t]] = (float*)(ws + alloc((size_t)fsize[t] * 4));

    DetectArgs da;
    da.src[0] = d_in[0]; da.nhalf[0] = N * 75; da.fi[0] = 0;
    da.src[1] = d_in[1]; da.nhalf[1] = E * 16; da.fi[1] = 1;
    for (int t = 0; t < 15; ++t) { da.src[2 + t] = d_in[fidx[t]]; da.nhalf[2 + t] = fsize[t]; da.fi[2 + t] = fidx[t]; }
    k_dtype_all<<<17, 256, 0, stream>>>(da, fl);
    k_i64<<<1, 256, 0, stream>>>((const unsigned int*)d_in[2], (long long)2 * E, flagE);
    k_i64<<<1, 256, 0, stream>>>((const unsigned int*)d_in[3], (long long)N, flagG);

    CvtArgs ca;
    int pre = 0;
    for (int t = 0; t < 15; ++t) {
        ca.src[t] = d_in[fidx[t]]; ca.dst[t] = F[fidx[t]]; ca.n[t] = fsize[t]; ca.fi[t] = fidx[t];
        ca.pre[t] = pre; pre += (fsize[t] + 255) / 256;
    }
    ca.pre[15] = pre;
    k_cvt_all<<<pre, 256, 0, stream>>>(ca, fl);
    k_t2<<<4096 * 16 / 256, 256, 0, stream>>>(d_in[8], w2T, fl + 8);
    k_gpack<<<(64 * 384 + 255) / 256, 256, 0, stream>>>(F[11], F[12], wpk);

    hipMemsetAsync(counts, 0, (size_t)N * 4, stream);
    hipMemsetAsync(qstar, 0, (size_t)(B * 128 + B * 64 + B * 64) * 4, stream);

    k_counts<<<E / 256, 256, 0, stream>>>(d_in[2], flagE, counts, E);
    k_rowptr<<<(B + 1 + 255) / 256, 256, 0, stream>>>(d_in[3], flagG, rowptr, N, B);
    k_lin0<<<N / 4, 256, 0, stream>>>(d_in[0], F[4], F[5], outbuf, fl + 0);
    k1_h1<<<E / 2, 256, 0, stream>>>(d_in[1], F[6], F[7], h1, fl + 1);

    for (int it = 0; it < 3; ++it) {
        hipMemsetAsync(agg, 0, (size_t)N * 64 * 4, stream);
        k23_fused<<<E / 64, 256, 0, stream>>>(h1, w2T, F[9], outbuf, d_in[2], flagE, agg);
        k4_gru<<<N / 64, 256, 0, stream>>>(agg, counts, F[10], wpk, F[13], F[14], outbuf);
    }
    for (int t = 0; t < 3; ++t) {
        k5_fused<<<B, 256, 0, stream>>>(qstar, hsb, csb, F[15], F[16], F[17], F[18], outbuf, rowptr);
    }
    k_out<<<(out_size + 255) / 256, 256, 0, stream>>>(qstar, outbuf, (float*)d_out,
                                                      B * 128, N * 64, out_size);
}